// Round 1
// baseline (845.865 us; speedup 1.0000x reference)
//
#include <hip/hip_runtime.h>

#define N_NODES 100000
#define N_EDGES 1600000
#define D 64

// ---------------------------------------------------------------------------
// Phase 1: edge scatter. One wave (64 lanes) per edge.
// lane i:  agg[dst][i] += feat[src][i]   (coalesced 256B row gather + RMW)
// lane 0:  deg[dst]    += 1
// agg lives in d_out (same shape as the final output).
// ---------------------------------------------------------------------------
__global__ __launch_bounds__(256) void sage_scatter(
    const float* __restrict__ feat,
    const int*   __restrict__ src,
    const int*   __restrict__ dst,
    float*       __restrict__ agg,   // = d_out
    float*       __restrict__ deg)
{
    const int gtid = blockIdx.x * blockDim.x + threadIdx.x;
    const int edge = gtid >> 6;
    const int lane = gtid & 63;
    if (edge >= N_EDGES) return;

    const int s = src[edge];
    const int d = dst[edge];
    const float v = feat[s * D + lane];
    atomicAdd(&agg[d * D + lane], v);
    if (lane == 0) atomicAdd(&deg[d], 1.0f);
}

// ---------------------------------------------------------------------------
// Phase 2: per-node dense update (in place over d_out):
//   out[n][c] = sum_k feat[n][k]*Ws[c][k] + (agg[n][k]/max(deg,1))*Wn[c][k]
// 256 threads = 4 nodes/block, thread = (node_local, out_col).
// W matrices staged TRANSPOSED in LDS: inner-loop read WsT[k*64+c] is
// lane-consecutive (2-way bank aliasing = free); feat/agg row reads are
// same-address broadcasts (free).
// ---------------------------------------------------------------------------
__global__ __launch_bounds__(256) void sage_update(
    const float* __restrict__ feat,
    const float* __restrict__ Ws,
    const float* __restrict__ Wn,
    const float* __restrict__ deg,
    float*       __restrict__ out)   // holds agg on entry
{
    __shared__ float WsT[D * D];      // 16 KB
    __shared__ float WnT[D * D];      // 16 KB
    __shared__ float featLDS[4 * D];  // 1 KB
    __shared__ float aggLDS[4 * D];   // 1 KB

    const int t = threadIdx.x;

    // Stage W transposed: WsT[k][c] = Ws[c][k]
    for (int i = t; i < D * D; i += 256) {
        const int r = i >> 6;     // output col
        const int k = i & 63;     // input dim
        WsT[k * D + r] = Ws[i];
        WnT[k * D + r] = Wn[i];
    }

    const int base = blockIdx.x * 4;
    for (int i = t; i < 4 * D; i += 256) {
        const int n = base + (i >> 6);
        featLDS[i] = feat[n * D + (i & 63)];
        aggLDS[i]  = out[n * D + (i & 63)];   // agg read BEFORE barrier
    }
    __syncthreads();

    const int nl = t >> 6;       // node within block
    const int c  = t & 63;       // output column
    const int n  = base + nl;

    const float* fr = &featLDS[nl * D];
    const float* ar = &aggLDS[nl * D];

    float accs = 0.0f, accn = 0.0f;
    #pragma unroll
    for (int k = 0; k < D; ++k) {
        accs = fmaf(fr[k], WsT[k * D + c], accs);
        accn = fmaf(ar[k], WnT[k * D + c], accn);
    }

    const float inv = 1.0f / fmaxf(deg[n], 1.0f);
    out[n * D + c] = accs + accn * inv;
}

extern "C" void kernel_launch(void* const* d_in, const int* in_sizes, int n_in,
                              void* d_out, int out_size, void* d_ws, size_t ws_size,
                              hipStream_t stream) {
    const float* feat = (const float*)d_in[0];
    const int*   src  = (const int*)d_in[1];
    const int*   dst  = (const int*)d_in[2];
    const float* Ws   = (const float*)d_in[3];
    const float* Wn   = (const float*)d_in[4];
    float* out = (float*)d_out;
    float* deg = (float*)d_ws;   // N_NODES floats = 400 KB

    // Zero accumulators each call (deterministic; graph-capture-safe).
    hipMemsetAsync(out, 0, (size_t)N_NODES * D * sizeof(float), stream);
    hipMemsetAsync(deg, 0, (size_t)N_NODES * sizeof(float), stream);

    // One wave per edge: E*64 threads / 256 = 400000 blocks.
    sage_scatter<<<(N_EDGES * 64) / 256, 256, 0, stream>>>(feat, src, dst, out, deg);

    // 4 nodes per 256-thread block: 25000 blocks.
    sage_update<<<N_NODES / 4, 256, 0, stream>>>(feat, Ws, Wn, deg, out);
}

// Round 2
// 490.232 us; speedup vs baseline: 1.7254x; 1.7254x over previous
//
#include <hip/hip_runtime.h>

#define N_NODES 100000
#define N_EDGES 1600000
#define D 64

// Update-kernel geometry: 1000 blocks × 25 passes × 4 nodes = 100000 exactly.
#define UPD_BLOCKS 1000
#define NPP 4                              // nodes per pass
#define PASSES (N_NODES / (UPD_BLOCKS * NPP))   // 25

// ---------------------------------------------------------------------------
// Phase 1: edge scatter (unchanged from R1). One wave per edge.
// ---------------------------------------------------------------------------
__global__ __launch_bounds__(256) void sage_scatter(
    const float* __restrict__ feat,
    const int*   __restrict__ src,
    const int*   __restrict__ dst,
    float*       __restrict__ agg,   // = d_out
    float*       __restrict__ deg)
{
    const int gtid = blockIdx.x * blockDim.x + threadIdx.x;
    const int edge = gtid >> 6;
    const int lane = gtid & 63;
    if (edge >= N_EDGES) return;

    const int s = src[edge];
    const int d = dst[edge];
    const float v = feat[s * D + lane];
    atomicAdd(&agg[d * D + lane], v);
    if (lane == 0) atomicAdd(&deg[d], 1.0f);
}

// ---------------------------------------------------------------------------
// Phase 2: per-node dense update, W IN REGISTERS.
//   thread = (node-in-pass nl = t>>6, out column c = t&63)
//   ws[16]/wn[16] float4 = W_self[c][:], W_neigh[c][:]  (128 VGPRs, loaded once)
//   feat/agg rows staged coalesced to LDS (double-buffered, 2KB/buf),
//   consumed as wave-uniform float4 broadcasts (conflict-free).
//   out written in place over the agg buffer (block-private contiguous range).
// ---------------------------------------------------------------------------
__global__ __launch_bounds__(256) void sage_update(
    const float* __restrict__ feat,
    const float* __restrict__ Ws,
    const float* __restrict__ Wn,
    const float* __restrict__ deg,
    float* out)   // holds agg on entry; no restrict (read+write alias)
{
    __shared__ float4 fLDS[2][NPP * 16];   // 2 × 1KB
    __shared__ float4 aLDS[2][NPP * 16];   // 2 × 1KB

    const int t  = threadIdx.x;
    const int c  = t & 63;    // output column (lane)
    const int nl = t >> 6;    // node within pass (wave id)

    // --- W rows into registers (once per thread lifetime) ---
    const float4* Ws4 = (const float4*)Ws;
    const float4* Wn4 = (const float4*)Wn;
    float4 ws[16], wn[16];
    #pragma unroll
    for (int j = 0; j < 16; ++j) {
        ws[j] = Ws4[c * 16 + j];
        wn[j] = Wn4[c * 16 + j];
    }

    const int node0 = blockIdx.x * (NPP * PASSES);   // block-private node range
    const float4* feat4 = (const float4*)feat;
    const float4* out4  = (const float4*)out;

    // --- prologue: stage pass 0 (threads 0..127: 64 feat + 64 agg float4s) ---
    {
        const int b4 = node0 * 16;        // float4 index of pass-0 tile
        if (t < 64)        fLDS[0][t]      = feat4[b4 + t];
        else if (t < 128)  aLDS[0][t - 64] = out4[b4 + (t - 64)];
    }
    __syncthreads();

    for (int p = 0; p < PASSES; ++p) {
        const int buf  = p & 1;
        const int base = node0 + p * NPP;

        // prefetch next pass's tile into registers (hides HBM latency)
        float4 fnx, anx;
        const bool pref = (p + 1 < PASSES) && (t < 128);
        if (pref) {
            const int b4 = (node0 + (p + 1) * NPP) * 16;
            if (t < 64) fnx = feat4[b4 + t];
            else        anx = out4[b4 + (t - 64)];
        }

        // compute: 128 FMAs from wave-uniform LDS broadcasts
        float accs = 0.0f, accn = 0.0f;
        #pragma unroll
        for (int j = 0; j < 16; ++j) {
            const float4 f = fLDS[buf][nl * 16 + j];
            accs = fmaf(f.x, ws[j].x, accs);
            accs = fmaf(f.y, ws[j].y, accs);
            accs = fmaf(f.z, ws[j].z, accs);
            accs = fmaf(f.w, ws[j].w, accs);
            const float4 a = aLDS[buf][nl * 16 + j];
            accn = fmaf(a.x, wn[j].x, accn);
            accn = fmaf(a.y, wn[j].y, accn);
            accn = fmaf(a.z, wn[j].z, accn);
            accn = fmaf(a.w, wn[j].w, accn);
        }

        const int   n   = base + nl;
        const float inv = 1.0f / fmaxf(deg[n], 1.0f);
        out[n * D + c] = accs + accn * inv;   // coalesced 256B per wave

        // write prefetched tile to the other buffer (its readers finished
        // at the barrier ending pass p-1)
        if (pref) {
            if (t < 64) fLDS[buf ^ 1][t]      = fnx;
            else        aLDS[buf ^ 1][t - 64] = anx;
        }
        __syncthreads();
    }
}

extern "C" void kernel_launch(void* const* d_in, const int* in_sizes, int n_in,
                              void* d_out, int out_size, void* d_ws, size_t ws_size,
                              hipStream_t stream) {
    const float* feat = (const float*)d_in[0];
    const int*   src  = (const int*)d_in[1];
    const int*   dst  = (const int*)d_in[2];
    const float* Ws   = (const float*)d_in[3];
    const float* Wn   = (const float*)d_in[4];
    float* out = (float*)d_out;
    float* deg = (float*)d_ws;   // N_NODES floats = 400 KB

    hipMemsetAsync(out, 0, (size_t)N_NODES * D * sizeof(float), stream);
    hipMemsetAsync(deg, 0, (size_t)N_NODES * sizeof(float), stream);

    sage_scatter<<<(N_EDGES * 64) / 256, 256, 0, stream>>>(feat, src, dst, out, deg);
    sage_update<<<UPD_BLOCKS, 256, 0, stream>>>(feat, Ws, Wn, deg, out);
}

// Round 3
// 336.911 us; speedup vs baseline: 2.5106x; 1.4551x over previous
//
#include <hip/hip_runtime.h>

#define N_NODES 100000
#define N_EDGES 1600000
#define D 64

#define UPD_BLOCKS 1000
#define NPP 4
#define PASSES (N_NODES / (UPD_BLOCKS * NPP))   // 25

#define SCAN_BLOCKS ((N_NODES + 255) / 256)     // 391

// ---- d_ws layout (bytes) ----
#define WS_CNT      0u                          // int[N_NODES]
#define WS_OFF      400000u                     // int[N_NODES]
#define WS_CUR      800000u                     // int[N_NODES]
#define WS_BSUM     1200000u                    // int[512]
#define WS_SORTED   1202048u                    // int[N_EDGES]
#define WS_NEED     (1202048u + 4u * N_EDGES)   // ~7.6 MB
#define WS_DEG      0u                          // fallback path: float[N_NODES]

// ===========================================================================
// CSR build
// ===========================================================================
__global__ __launch_bounds__(256) void k_count(
    const int* __restrict__ dst, int* __restrict__ cnt)
{
    const int e = blockIdx.x * 256 + threadIdx.x;
    if (e < N_EDGES) atomicAdd(&cnt[dst[e]], 1);
}

// per-block exclusive scan of counts; block totals to bsum
__global__ __launch_bounds__(256) void k_scan_block(
    const int* __restrict__ cnt, int* __restrict__ off, int* __restrict__ bsum)
{
    __shared__ int tmp[256];
    const int t = threadIdx.x;
    const int i = blockIdx.x * 256 + t;
    const int v = (i < N_NODES) ? cnt[i] : 0;
    tmp[t] = v;
    __syncthreads();
    for (int o = 1; o < 256; o <<= 1) {
        const int x = (t >= o) ? tmp[t - o] : 0;
        __syncthreads();
        tmp[t] += x;
        __syncthreads();
    }
    if (i < N_NODES) off[i] = tmp[t] - v;              // exclusive within block
    if (t == 255) bsum[blockIdx.x] = tmp[255];
}

// exclusive scan of the 391 block sums (in place), single block
__global__ __launch_bounds__(512) void k_scan_sums(int* __restrict__ bsum)
{
    __shared__ int tmp[512];
    const int t = threadIdx.x;
    const int v = (t < SCAN_BLOCKS) ? bsum[t] : 0;
    tmp[t] = v;
    __syncthreads();
    for (int o = 1; o < 512; o <<= 1) {
        const int x = (t >= o) ? tmp[t - o] : 0;
        __syncthreads();
        tmp[t] += x;
        __syncthreads();
    }
    if (t < SCAN_BLOCKS) bsum[t] = tmp[t] - v;
}

__global__ __launch_bounds__(256) void k_add_off(
    int* __restrict__ off, const int* __restrict__ bsum, int* __restrict__ cur)
{
    const int i = blockIdx.x * 256 + threadIdx.x;
    if (i < N_NODES) {
        const int o = off[i] + bsum[blockIdx.x];
        off[i] = o;
        cur[i] = o;
    }
}

__global__ __launch_bounds__(256) void k_bucket(
    const int* __restrict__ src, const int* __restrict__ dst,
    int* __restrict__ cur, int* __restrict__ sorted)
{
    const int e = blockIdx.x * 256 + threadIdx.x;
    if (e < N_EDGES) {
        const int idx = atomicAdd(&cur[dst[e]], 1);
        sorted[idx] = src[e];
    }
}

// ===========================================================================
// Pull aggregation: one wave per dst node; lane = feature column.
// Writes the MEAN directly into out.
// ===========================================================================
__global__ __launch_bounds__(256) void k_aggregate(
    const float* __restrict__ feat,
    const int*   __restrict__ off,
    const int*   __restrict__ cnt,
    const int*   __restrict__ sorted,
    float*       __restrict__ out)
{
    const int gtid = blockIdx.x * 256 + threadIdx.x;
    const int n    = gtid >> 6;
    const int lane = gtid & 63;
    if (n >= N_NODES) return;

    const int start = off[n];
    const int deg   = cnt[n];
    const int end   = start + deg;

    float a0 = 0.f, a1 = 0.f, a2 = 0.f, a3 = 0.f;
    int e = start;
    for (; e + 4 <= end; e += 4) {
        const int s0 = __builtin_amdgcn_readfirstlane(sorted[e]);
        const int s1 = __builtin_amdgcn_readfirstlane(sorted[e + 1]);
        const int s2 = __builtin_amdgcn_readfirstlane(sorted[e + 2]);
        const int s3 = __builtin_amdgcn_readfirstlane(sorted[e + 3]);
        a0 += feat[s0 * D + lane];
        a1 += feat[s1 * D + lane];
        a2 += feat[s2 * D + lane];
        a3 += feat[s3 * D + lane];
    }
    for (; e < end; ++e) {
        const int s = __builtin_amdgcn_readfirstlane(sorted[e]);
        a0 += feat[s * D + lane];
    }

    const float inv = 1.0f / (float)max(deg, 1);
    out[n * D + lane] = ((a0 + a1) + (a2 + a3)) * inv;
}

// ===========================================================================
// Dense update (R2 structure, W in registers, double-buffered LDS tiles).
// DIV: whether to divide the neigh term by deg (fallback path only).
// ===========================================================================
template <bool DIV>
__global__ __launch_bounds__(256) void sage_update(
    const float* __restrict__ feat,
    const float* __restrict__ Ws,
    const float* __restrict__ Wn,
    const float* __restrict__ deg,
    float* out)
{
    __shared__ float4 fLDS[2][NPP * 16];
    __shared__ float4 aLDS[2][NPP * 16];

    const int t  = threadIdx.x;
    const int c  = t & 63;
    const int nl = t >> 6;

    const float4* Ws4 = (const float4*)Ws;
    const float4* Wn4 = (const float4*)Wn;
    float4 ws[16], wn[16];
    #pragma unroll
    for (int j = 0; j < 16; ++j) {
        ws[j] = Ws4[c * 16 + j];
        wn[j] = Wn4[c * 16 + j];
    }

    const int node0 = blockIdx.x * (NPP * PASSES);
    const float4* feat4 = (const float4*)feat;
    const float4* out4  = (const float4*)out;

    {
        const int b4 = node0 * 16;
        if (t < 64)        fLDS[0][t]      = feat4[b4 + t];
        else if (t < 128)  aLDS[0][t - 64] = out4[b4 + (t - 64)];
    }
    __syncthreads();

    for (int p = 0; p < PASSES; ++p) {
        const int buf  = p & 1;
        const int base = node0 + p * NPP;

        float4 fnx, anx;
        const bool pref = (p + 1 < PASSES) && (t < 128);
        if (pref) {
            const int b4 = (node0 + (p + 1) * NPP) * 16;
            if (t < 64) fnx = feat4[b4 + t];
            else        anx = out4[b4 + (t - 64)];
        }

        float accs = 0.0f, accn = 0.0f;
        #pragma unroll
        for (int j = 0; j < 16; ++j) {
            const float4 f = fLDS[buf][nl * 16 + j];
            accs = fmaf(f.x, ws[j].x, accs);
            accs = fmaf(f.y, ws[j].y, accs);
            accs = fmaf(f.z, ws[j].z, accs);
            accs = fmaf(f.w, ws[j].w, accs);
            const float4 a = aLDS[buf][nl * 16 + j];
            accn = fmaf(a.x, wn[j].x, accn);
            accn = fmaf(a.y, wn[j].y, accn);
            accn = fmaf(a.z, wn[j].z, accn);
            accn = fmaf(a.w, wn[j].w, accn);
        }

        const int n = base + nl;
        if (DIV) {
            const float inv = 1.0f / fmaxf(deg[n], 1.0f);
            out[n * D + c] = accs + accn * inv;
        } else {
            out[n * D + c] = accs + accn;
        }

        if (pref) {
            if (t < 64) fLDS[buf ^ 1][t]      = fnx;
            else        aLDS[buf ^ 1][t - 64] = anx;
        }
        __syncthreads();
    }
}

// fallback scatter (R2)
__global__ __launch_bounds__(256) void sage_scatter(
    const float* __restrict__ feat,
    const int*   __restrict__ src,
    const int*   __restrict__ dst,
    float*       __restrict__ agg,
    float*       __restrict__ deg)
{
    const int gtid = blockIdx.x * blockDim.x + threadIdx.x;
    const int edge = gtid >> 6;
    const int lane = gtid & 63;
    if (edge >= N_EDGES) return;
    const int s = src[edge];
    const int d = dst[edge];
    atomicAdd(&agg[d * D + lane], feat[s * D + lane]);
    if (lane == 0) atomicAdd(&deg[d], 1.0f);
}

extern "C" void kernel_launch(void* const* d_in, const int* in_sizes, int n_in,
                              void* d_out, int out_size, void* d_ws, size_t ws_size,
                              hipStream_t stream) {
    const float* feat = (const float*)d_in[0];
    const int*   src  = (const int*)d_in[1];
    const int*   dst  = (const int*)d_in[2];
    const float* Ws   = (const float*)d_in[3];
    const float* Wn   = (const float*)d_in[4];
    float* out = (float*)d_out;
    char*  ws  = (char*)d_ws;

    if (ws_size >= WS_NEED) {
        int* cnt    = (int*)(ws + WS_CNT);
        int* off    = (int*)(ws + WS_OFF);
        int* cur    = (int*)(ws + WS_CUR);
        int* bsum   = (int*)(ws + WS_BSUM);
        int* sorted = (int*)(ws + WS_SORTED);

        hipMemsetAsync(cnt, 0, (size_t)N_NODES * sizeof(int), stream);

        const int EB = (N_EDGES + 255) / 256;   // 6250
        k_count    <<<EB,          256, 0, stream>>>(dst, cnt);
        k_scan_block<<<SCAN_BLOCKS, 256, 0, stream>>>(cnt, off, bsum);
        k_scan_sums <<<1,           512, 0, stream>>>(bsum);
        k_add_off  <<<SCAN_BLOCKS, 256, 0, stream>>>(off, bsum, cur);
        k_bucket   <<<EB,          256, 0, stream>>>(src, dst, cur, sorted);

        k_aggregate<<<(N_NODES * 64 + 255) / 256, 256, 0, stream>>>(
            feat, off, cnt, sorted, out);

        sage_update<false><<<UPD_BLOCKS, 256, 0, stream>>>(
            feat, Ws, Wn, nullptr, out);
    } else {
        float* deg = (float*)(ws + WS_DEG);
        hipMemsetAsync(out, 0, (size_t)N_NODES * D * sizeof(float), stream);
        hipMemsetAsync(deg, 0, (size_t)N_NODES * sizeof(float), stream);
        sage_scatter<<<(N_EDGES * 64) / 256, 256, 0, stream>>>(feat, src, dst, out, deg);
        sage_update<true><<<UPD_BLOCKS, 256, 0, stream>>>(feat, Ws, Wn, deg, out);
    }
}